// Round 7
// baseline (533.580 us; speedup 1.0000x reference)
//
#include <hip/hip_runtime.h>
#include <hip/hip_bf16.h>

#define B_ 4
#define T_ 2048
#define E_ 1024
#define H_ 16
#define HS_ 64
#define DFF_ 4096
#define M_ (B_ * T_)   // 8192 tokens
#define LDQ_ (3 * E_)  // qkv fused row stride

typedef __bf16 bf16_t;
typedef __bf16 bf16x4 __attribute__((ext_vector_type(4)));
typedef __bf16 bf16x8 __attribute__((ext_vector_type(8)));
typedef float f32x4 __attribute__((ext_vector_type(4)));

#define AS1 __attribute__((address_space(1)))
#define AS3 __attribute__((address_space(3)))

__device__ __forceinline__ void gload_lds16(const void* g, void* l) {
  __builtin_amdgcn_global_load_lds((AS1 void*)(g), (AS3 void*)(l), 16, 0, 0);
}

// ---------------------------------------------------------------------------
// Weight convert+transpose: W fp32 [Krows][Ncols] -> Wt bf16 [Ncols][Krows]
// ---------------------------------------------------------------------------
__global__ __launch_bounds__(256) void wtrans_kernel(
    const float* __restrict__ W, bf16_t* __restrict__ Wt, int Krows, int Ncols) {
  __shared__ float tile[32][33];
  int tx = threadIdx.x, ty = threadIdx.y;  // (32,8)
  int n0 = blockIdx.x * 32, k0 = blockIdx.y * 32;
#pragma unroll
  for (int i = 0; i < 32; i += 8)
    tile[ty + i][tx] = W[(long)(k0 + ty + i) * Ncols + n0 + tx];
  __syncthreads();
#pragma unroll
  for (int i = 0; i < 32; i += 8)
    Wt[(long)(n0 + ty + i) * Krows + k0 + tx] = (bf16_t)tile[tx][ty + i];
}

// bias concat: [bq | bk | bv] -> 3072 floats
__global__ __launch_bounds__(256) void bcat_kernel(const float* a, const float* b,
                                                   const float* c, float* o) {
  int i = blockIdx.x * 256 + threadIdx.x;
  o[i] = i < 1024 ? a[i] : (i < 2048 ? b[i - 1024] : c[i - 2048]);
}

// ---------------------------------------------------------------------------
// LayerNorm: fp32 [M][1024] -> bf16 [M][1024]
// ---------------------------------------------------------------------------
__global__ __launch_bounds__(256) void layernorm_kernel(
    const float* __restrict__ in, const float* __restrict__ g,
    const float* __restrict__ b, bf16_t* __restrict__ out) {
  int row = blockIdx.x;
  int tid = threadIdx.x;
  const float4* inr = (const float4*)(in + (long)row * E_);
  float4 v = inr[tid];
  float s = v.x + v.y + v.z + v.w;
  float ss = v.x * v.x + v.y * v.y + v.z * v.z + v.w * v.w;
#pragma unroll
  for (int o = 32; o; o >>= 1) {
    s += __shfl_xor(s, o);
    ss += __shfl_xor(ss, o);
  }
  __shared__ float red[8];
  int wv = tid >> 6;
  if ((tid & 63) == 0) {
    red[wv] = s;
    red[4 + wv] = ss;
  }
  __syncthreads();
  s = red[0] + red[1] + red[2] + red[3];
  ss = red[4] + red[5] + red[6] + red[7];
  float mu = s * (1.f / E_);
  float var = ss * (1.f / E_) - mu * mu;
  float rs = rsqrtf(var + 1e-5f);
  int ci = tid * 4;
  float4 gv = *(const float4*)(g + ci);
  float4 bv = *(const float4*)(b + ci);
  long o0 = (long)row * E_ + ci;
  out[o0 + 0] = (bf16_t)((v.x - mu) * rs * gv.x + bv.x);
  out[o0 + 1] = (bf16_t)((v.y - mu) * rs * gv.y + bv.y);
  out[o0 + 2] = (bf16_t)((v.z - mu) * rs * gv.z + bv.z);
  out[o0 + 3] = (bf16_t)((v.w - mu) * rs * gv.w + bv.w);
}

// ---------------------------------------------------------------------------
// GEMM: C[M,N] = A[M,K] * Bt[N,K]^T + bias. 256x128 block tile, BK=64,
// 4 waves in 2x2, wave tile 128x64 (af[8] x bfr[4] -> 32 MFMA per BK=32:
// 1.33x more MACs per ds_read_b128 than 64x64; 64 MFMA per barrier).
// global_load_lds width-16 staging into XOR-swizzled flat LDS; XCD-aware
// block remap (panel-mates share an XCD's L2). Scalar wave-coalesced epilogue.
// MODE 0: bf16 store; MODE 1: fp32 store of (C + resid); MODE 2: bf16 relu.
// Requires gridDim.y % 8 == 0? No: (gx*gy)%8==0; here gy=32 always.
// ---------------------------------------------------------------------------
template <int MODE>
__global__ __launch_bounds__(256, 2) void gemm_bt_kernel(
    const bf16_t* __restrict__ A, const bf16_t* __restrict__ Bt,
    const float* __restrict__ bias, const float* __restrict__ resid,
    void* __restrict__ out, int N, int K) {
  __shared__ bf16_t As[256 * 64];
  __shared__ bf16_t Bs[128 * 64];
  const int tid = threadIdx.x;
  const int lane = tid & 63;
  const int wave = tid >> 6;
  const int wr = wave >> 1, wc = wave & 1;
  const int quad = lane >> 4, l16 = lane & 15;
  // XCD-aware remap:
  const int id = blockIdx.y * gridDim.x + blockIdx.x;
  const int xcd = id & 7;
  const int k_ = id >> 3;
  const int bxr = k_ % gridDim.x;                  // col block
  const int byr = (k_ / gridDim.x) * 8 + xcd;      // row block
  const long rowBase = (long)byr * 256;
  const long colBase = (long)bxr * 128;

  f32x4 acc[8][4] = {};

  for (int k0 = 0; k0 < K; k0 += 64) {
    // stage A 256x64 (2048 chunks) and B 128x64 (1024 chunks); LDS chunk c
    // holds global chunk (row = c>>3, gcol = (c&7) ^ (row&7)).
#pragma unroll
    for (int i = 0; i < 8; ++i) {
      int c = i * 256 + tid;
      int row = c >> 3;
      int gcol = ((c & 7) ^ (row & 7)) * 8;
      gload_lds16(&A[(rowBase + row) * K + k0 + gcol],
                  As + (i * 256 + wave * 64) * 8);
    }
#pragma unroll
    for (int i = 0; i < 4; ++i) {
      int c = i * 256 + tid;
      int row = c >> 3;
      int gcol = ((c & 7) ^ (row & 7)) * 8;
      gload_lds16(&Bt[(colBase + row) * K + k0 + gcol],
                  Bs + (i * 256 + wave * 64) * 8);
    }
    __syncthreads();
#pragma unroll
    for (int kk = 0; kk < 2; ++kk) {
      bf16x8 af[8], bfr[4];
#pragma unroll
      for (int i = 0; i < 8; ++i) {
        int rowA = wr * 128 + i * 16 + l16;
        af[i] = *(const bf16x8*)&As[(rowA * 8 + ((quad + 4 * kk) ^ (rowA & 7))) * 8];
      }
#pragma unroll
      for (int i = 0; i < 4; ++i) {
        int rowB = wc * 64 + i * 16 + l16;
        bfr[i] = *(const bf16x8*)&Bs[(rowB * 8 + ((quad + 4 * kk) ^ (rowB & 7))) * 8];
      }
#pragma unroll
      for (int mi = 0; mi < 8; ++mi)
#pragma unroll
        for (int ni = 0; ni < 4; ++ni)
          acc[mi][ni] = __builtin_amdgcn_mfma_f32_16x16x32_bf16(
              af[mi], bfr[ni], acc[mi][ni], 0, 0, 0);
    }
    __syncthreads();
  }

#pragma unroll
  for (int mi = 0; mi < 8; ++mi) {
#pragma unroll
    for (int ni = 0; ni < 4; ++ni) {
      int colg = (int)colBase + wc * 64 + ni * 16 + l16;
      float bv = bias[colg];
#pragma unroll
      for (int r = 0; r < 4; ++r) {
        long rowg = rowBase + wr * 128 + mi * 16 + quad * 4 + r;
        float v = acc[mi][ni][r] + bv;
        long idx = rowg * N + colg;
        if (MODE == 0) {
          ((bf16_t*)out)[idx] = (bf16_t)v;
        } else if (MODE == 1) {
          ((float*)out)[idx] = v + resid[idx];
        } else {
          ((bf16_t*)out)[idx] = (bf16_t)fmaxf(v, 0.f);
        }
      }
    }
  }
}

// ---------------------------------------------------------------------------
// V transpose: qkv bf16 [B*T][3072] v-part -> vt bf16 [b*h][d=64][t=2048]
// ---------------------------------------------------------------------------
__global__ __launch_bounds__(256) void vtrans_kernel(
    const bf16_t* __restrict__ qkv, bf16_t* __restrict__ vt) {
  __shared__ bf16_t tile[32][33];
  int tx = threadIdx.x, ty = threadIdx.y;  // (32,8)
  int t0 = blockIdx.x * 32;
  int d0 = (blockIdx.y & 1) * 32;
  int bh = blockIdx.y >> 1;
  int b = bh >> 4, hh = bh & 15;
#pragma unroll
  for (int i = 0; i < 32; i += 8)
    tile[ty + i][tx] =
        qkv[(long)(b * T_ + t0 + ty + i) * LDQ_ + 2 * E_ + hh * HS_ + d0 + tx];
  __syncthreads();
#pragma unroll
  for (int i = 0; i < 32; i += 8)
    vt[((long)bh * HS_ + d0 + ty + i) * T_ + t0 + tx] = tile[tx][ty + i];
}

// ---------------------------------------------------------------------------
// Causal flash attention, KV-split, no-max softmax. S^T form: compute
// S^T = K * Q^T, kv index in register dim: exp'd scores pack into b64 LDS
// writes, l is a per-lane scalar (2 shuffles at end only). Q pre-scaled by
// 0.125 (exact in bf16). O computed transposed; 8B stores.
// Block = 4 waves = 128 Q rows (q-tile ti), KV chunk of <=12 iters of 64.
// splits(ti) = ti/6+1 -> 30 blocks per bh. Multi-split tiles write normalized
// partials merged by flash_merge_kernel with w = l.
// ---------------------------------------------------------------------------
__global__ __launch_bounds__(256) void flash_attn_kernel(
    const bf16_t* __restrict__ qkv, const bf16_t* __restrict__ vt,
    bf16_t* __restrict__ attn, bf16_t* __restrict__ Opart,
    float* __restrict__ mlpart) {
  int gx = blockIdx.x;
  int ti = 0, sp = 0;
  for (int t = 0; t < 16; ++t) {
    int ns = t / 6 + 1;
    if (gx < ns) { ti = t; sp = gx; break; }
    gx -= ns;
  }
  const int nsplit = ti / 6 + 1;
  const int totIt = 2 * (ti + 1);
  const int jbeg = 12 * sp;
  const int jend = min(jbeg + 12, totIt);

  const int tid = threadIdx.x;
  const int lane = tid & 63, wave = tid >> 6;
  const int quad = lane >> 4, l16 = lane & 15;
  const int bh = blockIdx.y, b = bh >> 4, hh = bh & 15;
  const int q0 = ti * 128;
  const int qw = q0 + wave * 32;

  __shared__ __align__(16) bf16_t Ks[64][72];     // [kv][d]
  __shared__ __align__(16) bf16_t Vs[64][72];     // [d][kv]
  __shared__ __align__(16) bf16_t Ps[4][16][72];  // per-wave P^T [q=16][kv=64]

  const bf16_t* qb = qkv;
  const bf16_t* kb = qkv + E_;

  // Q fragments, pre-scaled by HS^-0.5 = 0.125 (power of 2: exact in bf16)
  bf16x8 aq[2][2];
#pragma unroll
  for (int s = 0; s < 2; ++s) {
    long base = (long)(b * T_ + qw + s * 16 + l16) * LDQ_ + hh * HS_ + quad * 8;
    aq[s][0] = *(const bf16x8*)&qb[base];
    aq[s][1] = *(const bf16x8*)&qb[base + 32];
#pragma unroll
    for (int e = 0; e < 8; ++e) {
      aq[s][0][e] = (bf16_t)((float)aq[s][0][e] * 0.125f);
      aq[s][1][e] = (bf16_t)((float)aq[s][1][e] * 0.125f);
    }
  }

  f32x4 o[2][4] = {};     // O^T accumulator: [s][nt]; row d=quad*4+r, col q=l16
  float lsum[2] = {};     // per-lane row sums (q = qs + l16)

  const int srow = tid >> 3;            // 0..31
  const int scol = (tid & 7) * 8;       // bf16 col offset (16B)

  for (int j = jbeg; j < jend; ++j) {
    int kv0 = j * 64;
    // ---- stage K tile [64][64] and V^T tile [64][64] ----
#pragma unroll
    for (int p = 0; p < 2; ++p) {
      int row = p * 32 + srow;
      *(uint4*)&Ks[row][scol] =
          *(const uint4*)&kb[(long)(b * T_ + kv0 + row) * LDQ_ + hh * HS_ + scol];
      *(uint4*)&Vs[row][scol] =
          *(const uint4*)&vt[((long)bh * HS_ + row) * T_ + kv0 + scol];
    }
    __syncthreads();

#pragma unroll
    for (int s = 0; s < 2; ++s) {
      int qs = qw + s * 16;
      if (kv0 <= qs + 15) {
        // ---- S^T = K * Q^T : rows kv (quad*4+r per sub), col q (l16) ----
        f32x4 sc[4];
#pragma unroll
        for (int sub = 0; sub < 4; ++sub) {
          f32x4 t = {};
          t = __builtin_amdgcn_mfma_f32_16x16x32_bf16(
              *(const bf16x8*)&Ks[sub * 16 + l16][quad * 8], aq[s][0], t, 0, 0, 0);
          t = __builtin_amdgcn_mfma_f32_16x16x32_bf16(
              *(const bf16x8*)&Ks[sub * 16 + l16][32 + quad * 8], aq[s][1], t, 0, 0, 0);
          sc[sub] = t;
        }
        // ---- causal mask (diagonal tiles only): kv > q -> -inf ----
        if (kv0 + 63 > qs) {
          int qcol = qs + l16;
#pragma unroll
          for (int sub = 0; sub < 4; ++sub)
#pragma unroll
            for (int r = 0; r < 4; ++r) {
              int kvrow = kv0 + sub * 16 + quad * 4 + r;
              if (kvrow > qcol) sc[sub][r] = -INFINITY;
            }
        }
        // ---- p = exp(s); l accumulates per-lane (all values same q) ----
        float part = 0.f;
#pragma unroll
        for (int sub = 0; sub < 4; ++sub) {
#pragma unroll
          for (int r = 0; r < 4; ++r) sc[sub][r] = __expf(sc[sub][r]);
          part += (sc[sub][0] + sc[sub][1]) + (sc[sub][2] + sc[sub][3]);
        }
        lsum[s] += part;
        // ---- P^T -> LDS: Ps[q][kv], 4 consecutive kv per lane -> b64 ----
#pragma unroll
        for (int sub = 0; sub < 4; ++sub) {
          bf16x4 pk;
#pragma unroll
          for (int r = 0; r < 4; ++r) pk[r] = (bf16_t)sc[sub][r];
          *(bf16x4*)&Ps[wave][l16][sub * 16 + quad * 4] = pk;
        }
        // ---- O^T += V^T * P^T (A=V-frag, B=P-frag; intra-wave, no barrier)
        bf16x8 ap0 = *(const bf16x8*)&Ps[wave][l16][quad * 8];
        bf16x8 ap1 = *(const bf16x8*)&Ps[wave][l16][32 + quad * 8];
#pragma unroll
        for (int nt = 0; nt < 4; ++nt) {
          o[s][nt] = __builtin_amdgcn_mfma_f32_16x16x32_bf16(
              *(const bf16x8*)&Vs[nt * 16 + l16][quad * 8], ap0, o[s][nt], 0, 0, 0);
          o[s][nt] = __builtin_amdgcn_mfma_f32_16x16x32_bf16(
              *(const bf16x8*)&Vs[nt * 16 + l16][32 + quad * 8], ap1, o[s][nt], 0, 0, 0);
        }
      }
    }
    __syncthreads();
  }

  // ---- l reduction across the 4 quads sharing each q ----
  float lval[2];
#pragma unroll
  for (int s = 0; s < 2; ++s) {
    float v = lsum[s];
    v += __shfl_xor(v, 16);
    v += __shfl_xor(v, 32);
    lval[s] = v;
  }

  if (nsplit == 1) {
#pragma unroll
    for (int s = 0; s < 2; ++s) {
      float inv = 1.f / lval[s];
      long rowg = (long)b * T_ + qw + s * 16 + l16;
#pragma unroll
      for (int nt = 0; nt < 4; ++nt) {
        bf16x4 pk;
#pragma unroll
        for (int r = 0; r < 4; ++r) pk[r] = (bf16_t)(o[s][nt][r] * inv);
        *(bf16x4*)&attn[rowg * E_ + hh * HS_ + nt * 16 + quad * 4] = pk;
      }
    }
  } else {
    int idx = (ti < 12) ? (ti - 6) * 2 + sp : 12 + (ti - 12) * 3 + sp;
    long slot = (long)bh * 24 + idx;
    bf16_t* op = Opart + slot * (128 * 64);
    float* ml = mlpart + slot * 256;
#pragma unroll
    for (int s = 0; s < 2; ++s) {
      float inv = 1.f / lval[s];
      int rloc = wave * 32 + s * 16 + l16;
#pragma unroll
      for (int nt = 0; nt < 4; ++nt) {
        bf16x4 pk;
#pragma unroll
        for (int r = 0; r < 4; ++r) pk[r] = (bf16_t)(o[s][nt][r] * inv);
        *(bf16x4*)&op[rloc * 64 + nt * 16 + quad * 4] = pk;
      }
      if (quad == 0) ml[rloc] = lval[s];
    }
  }
}

// ---------------------------------------------------------------------------
// Merge partials for multi-split q-tiles (ti = 6..15): O = sum(l_s*Ohat_s)/sum(l_s)
// grid: (10, 64bh), 256 threads: thread = row(128) * 2 + d-half(32).
// ---------------------------------------------------------------------------
__global__ __launch_bounds__(256) void flash_merge_kernel(
    const bf16_t* __restrict__ Opart, const float* __restrict__ mlpart,
    bf16_t* __restrict__ attn) {
  int ti = 6 + blockIdx.x;
  int bh = blockIdx.y, b = bh >> 4, hh = bh & 15;
  int ns = ti / 6 + 1;
  int base_idx = (ti < 12) ? (ti - 6) * 2 : 12 + (ti - 12) * 3;
  int r = threadIdx.x >> 1;
  int dh = (threadIdx.x & 1) * 32;

  float w[3], den = 0.f;
  for (int s = 0; s < ns; ++s) {
    long slot = (long)bh * 24 + base_idx + s;
    w[s] = mlpart[slot * 256 + r];
    den += w[s];
  }
  float inv = 1.f / den;
  float acc[32];
#pragma unroll
  for (int d = 0; d < 32; ++d) acc[d] = 0.f;
  for (int s = 0; s < ns; ++s) {
    long slot = (long)bh * 24 + base_idx + s;
    const bf16_t* op = Opart + slot * (128 * 64) + r * 64 + dh;
#pragma unroll
    for (int d = 0; d < 32; ++d) acc[d] += w[s] * (float)op[d];
  }
  long rowg = (long)b * T_ + ti * 128 + r;
  bf16_t* dst = attn + rowg * E_ + hh * HS_ + dh;
#pragma unroll
  for (int d = 0; d < 32; ++d) dst[d] = (bf16_t)(acc[d] * inv);
}

// ---------------------------------------------------------------------------
extern "C" void kernel_launch(void* const* d_in, const int* in_sizes, int n_in,
                              void* d_out, int out_size, void* d_ws,
                              size_t ws_size, hipStream_t stream) {
  const float* x = (const float*)d_in[0];
  const float* ln1_g = (const float*)d_in[1];
  const float* ln1_b = (const float*)d_in[2];
  const float* Wq = (const float*)d_in[3];
  const float* bq = (const float*)d_in[4];
  const float* Wk = (const float*)d_in[5];
  const float* bk = (const float*)d_in[6];
  const float* Wv = (const float*)d_in[7];
  const float* bv = (const float*)d_in[8];
  const float* Wp = (const float*)d_in[9];
  const float* bp = (const float*)d_in[10];
  const float* ln2_g = (const float*)d_in[11];
  const float* ln2_b = (const float*)d_in[12];
  const float* W1 = (const float*)d_in[13];
  const float* b1 = (const float*)d_in[14];
  const float* W2 = (const float*)d_in[15];
  const float* b2 = (const float*)d_in[16];
  float* out = (float*)d_out;

  const size_t MB = 1ull << 20;
  char* ws = (char*)d_ws;
  bf16_t* wqkvt = (bf16_t*)(ws + 0 * MB);   // [3072][1024] bf16 = 6 MB
  bf16_t* wpt   = (bf16_t*)(ws + 6 * MB);   // 2 MB
  bf16_t* w1t   = (bf16_t*)(ws + 8 * MB);   // 8 MB
  bf16_t* w2t   = (bf16_t*)(ws + 16 * MB);  // 8 MB
  float*  bqkv  = (float*)(ws + 24 * MB);   // 12 KB
  bf16_t* h     = (bf16_t*)(ws + 25 * MB);  // [8192][1024] 16 MB; reused: attn, h2
  bf16_t* qkvb  = (bf16_t*)(ws + 41 * MB);  // [8192][3072] 48 MB; reused: ff1
  bf16_t* vt    = (bf16_t*)(ws + 89 * MB);  // [64][64][2048] 16 MB
  float*  xmid  = (float*)(ws + 105 * MB);  // 32 MB -> ends 137 MB
  // flash scratch overlaps xmid temporally (dead before proj writes xmid):
  bf16_t* Opart = (bf16_t*)(ws + 105 * MB); // 1536 slots * 8192 bf16 = 25.2 MB
  float* mlpart = (float*)(ws + 131 * MB);  // 1536 * 256 fp32 = 1.5 MB
  bf16_t* attn  = h;                        // h dead after QKV gemm
  bf16_t* h2    = h;                        // attn dead after proj gemm
  bf16_t* ff1   = qkvb;                     // qkv+vt dead after flash

  dim3 tb(32, 8);
  // weight transposes into fused QKV layout [3072][1024]
  wtrans_kernel<<<dim3(E_ / 32, E_ / 32), tb, 0, stream>>>(Wq, wqkvt, E_, E_);
  wtrans_kernel<<<dim3(E_ / 32, E_ / 32), tb, 0, stream>>>(Wk, wqkvt + (long)E_ * E_, E_, E_);
  wtrans_kernel<<<dim3(E_ / 32, E_ / 32), tb, 0, stream>>>(Wv, wqkvt + 2l * E_ * E_, E_, E_);
  wtrans_kernel<<<dim3(E_ / 32, E_ / 32), tb, 0, stream>>>(Wp, wpt, E_, E_);
  wtrans_kernel<<<dim3(DFF_ / 32, E_ / 32), tb, 0, stream>>>(W1, w1t, E_, DFF_);
  wtrans_kernel<<<dim3(E_ / 32, DFF_ / 32), tb, 0, stream>>>(W2, w2t, DFF_, E_);
  bcat_kernel<<<12, 256, 0, stream>>>(bq, bk, bv, bqkv);

  // LN1
  layernorm_kernel<<<M_, 256, 0, stream>>>(x, ln1_g, ln1_b, h);

  // fused QKV gemm: [8192][3072], 256x128 tiles
  gemm_bt_kernel<0><<<dim3(3 * E_ / 128, M_ / 256), 256, 0, stream>>>(
      h, wqkvt, bqkv, nullptr, qkvb, 3 * E_, E_);

  // V transpose to [bh][d][t]
  vtrans_kernel<<<dim3(T_ / 32, 2 * B_ * H_), tb, 0, stream>>>(qkvb, vt);

  // flash attention, KV-split (30 uniform blocks per bh) + merge
  flash_attn_kernel<<<dim3(30, B_ * H_), 256, 0, stream>>>(qkvb, vt, attn,
                                                           Opart, mlpart);
  flash_merge_kernel<<<dim3(10, B_ * H_), 256, 0, stream>>>(Opart, mlpart, attn);

  // proj + residual -> xmid (fp32)
  gemm_bt_kernel<1><<<dim3(E_ / 128, M_ / 256), 256, 0, stream>>>(
      attn, wpt, bp, x, xmid, E_, E_);

  // LN2
  layernorm_kernel<<<M_, 256, 0, stream>>>(xmid, ln2_g, ln2_b, h2);

  // FFN
  gemm_bt_kernel<2><<<dim3(DFF_ / 128, M_ / 256), 256, 0, stream>>>(
      h2, w1t, b1, nullptr, ff1, DFF_, E_);
  gemm_bt_kernel<1><<<dim3(E_ / 128, M_ / 256), 256, 0, stream>>>(
      ff1, w2t, b2, xmid, out, E_, DFF_);
}

// Round 8
// 495.785 us; speedup vs baseline: 1.0762x; 1.0762x over previous
//
#include <hip/hip_runtime.h>
#include <hip/hip_bf16.h>

#define B_ 4
#define T_ 2048
#define E_ 1024
#define H_ 16
#define HS_ 64
#define DFF_ 4096
#define M_ (B_ * T_)   // 8192 tokens
#define LDQ_ (3 * E_)  // qkv fused row stride

typedef __bf16 bf16_t;
typedef __bf16 bf16x4 __attribute__((ext_vector_type(4)));
typedef __bf16 bf16x8 __attribute__((ext_vector_type(8)));
typedef float f32x4 __attribute__((ext_vector_type(4)));

#define AS1 __attribute__((address_space(1)))
#define AS3 __attribute__((address_space(3)))

__device__ __forceinline__ void gload_lds16(const void* g, void* l) {
  __builtin_amdgcn_global_load_lds((AS1 void*)(g), (AS3 void*)(l), 16, 0, 0);
}

// ---------------------------------------------------------------------------
// Weight convert+transpose: W fp32 [Krows][Ncols] -> Wt bf16 [Ncols][Krows]
// ---------------------------------------------------------------------------
__global__ __launch_bounds__(256) void wtrans_kernel(
    const float* __restrict__ W, bf16_t* __restrict__ Wt, int Krows, int Ncols) {
  __shared__ float tile[32][33];
  int tx = threadIdx.x, ty = threadIdx.y;  // (32,8)
  int n0 = blockIdx.x * 32, k0 = blockIdx.y * 32;
#pragma unroll
  for (int i = 0; i < 32; i += 8)
    tile[ty + i][tx] = W[(long)(k0 + ty + i) * Ncols + n0 + tx];
  __syncthreads();
#pragma unroll
  for (int i = 0; i < 32; i += 8)
    Wt[(long)(n0 + ty + i) * Krows + k0 + tx] = (bf16_t)tile[tx][ty + i];
}

// bias concat: [bq | bk | bv] -> 3072 floats
__global__ __launch_bounds__(256) void bcat_kernel(const float* a, const float* b,
                                                   const float* c, float* o) {
  int i = blockIdx.x * 256 + threadIdx.x;
  o[i] = i < 1024 ? a[i] : (i < 2048 ? b[i - 1024] : c[i - 2048]);
}

// ---------------------------------------------------------------------------
// LayerNorm: fp32 [M][1024] -> bf16 [M][1024]
// ---------------------------------------------------------------------------
__global__ __launch_bounds__(256) void layernorm_kernel(
    const float* __restrict__ in, const float* __restrict__ g,
    const float* __restrict__ b, bf16_t* __restrict__ out) {
  int row = blockIdx.x;
  int tid = threadIdx.x;
  const float4* inr = (const float4*)(in + (long)row * E_);
  float4 v = inr[tid];
  float s = v.x + v.y + v.z + v.w;
  float ss = v.x * v.x + v.y * v.y + v.z * v.z + v.w * v.w;
#pragma unroll
  for (int o = 32; o; o >>= 1) {
    s += __shfl_xor(s, o);
    ss += __shfl_xor(ss, o);
  }
  __shared__ float red[8];
  int wv = tid >> 6;
  if ((tid & 63) == 0) {
    red[wv] = s;
    red[4 + wv] = ss;
  }
  __syncthreads();
  s = red[0] + red[1] + red[2] + red[3];
  ss = red[4] + red[5] + red[6] + red[7];
  float mu = s * (1.f / E_);
  float var = ss * (1.f / E_) - mu * mu;
  float rs = rsqrtf(var + 1e-5f);
  int ci = tid * 4;
  float4 gv = *(const float4*)(g + ci);
  float4 bv = *(const float4*)(b + ci);
  long o0 = (long)row * E_ + ci;
  out[o0 + 0] = (bf16_t)((v.x - mu) * rs * gv.x + bv.x);
  out[o0 + 1] = (bf16_t)((v.y - mu) * rs * gv.y + bv.y);
  out[o0 + 2] = (bf16_t)((v.z - mu) * rs * gv.z + bv.z);
  out[o0 + 3] = (bf16_t)((v.w - mu) * rs * gv.w + bv.w);
}

// ---------------------------------------------------------------------------
// GEMM: C[M,N] = A[M,K] * Bt[N,K]^T + bias. 128x128 tile, BK=64, 4 waves,
// DOUBLE-BUFFERED global_load_lds staging (2x32KB LDS, still 2 blocks/CU):
// prefetch tile k+1 into idle buffer before computing tile k, so the
// barrier's vmcnt(0) drain overlaps 64 MFMA of compute. XOR-swizzled LDS;
// XCD-aware block remap (panel-mates share an XCD L2). Scalar coalesced
// epilogue. r7 lesson: 256-row tile -> 1 block/CU killed overlap; stay 128.
// MODE 0: bf16 store; MODE 1: fp32 store of (C + resid); MODE 2: bf16 relu.
// ---------------------------------------------------------------------------
template <int MODE>
__global__ __launch_bounds__(256, 2) void gemm_bt_kernel(
    const bf16_t* __restrict__ A, const bf16_t* __restrict__ Bt,
    const float* __restrict__ bias, const float* __restrict__ resid,
    void* __restrict__ out, int N, int K) {
  __shared__ bf16_t As[2][128 * 64];
  __shared__ bf16_t Bs[2][128 * 64];
  const int tid = threadIdx.x;
  const int lane = tid & 63;
  const int wave = tid >> 6;
  const int wr = wave >> 1, wc = wave & 1;
  const int quad = lane >> 4, l16 = lane & 15;
  // XCD-aware remap:
  const int id = blockIdx.y * gridDim.x + blockIdx.x;
  const int xcd = id & 7;
  const int k_ = id >> 3;
  const int bxr = k_ % gridDim.x;                  // col block
  const int byr = (k_ / gridDim.x) * 8 + xcd;      // row block
  const long rowBase = (long)byr * 128;
  const long colBase = (long)bxr * 128;

  f32x4 acc[4][4] = {};

  // stage one 128x64 A-tile + B-tile into buffer `buf` (async, no wait)
  auto stage = [&](int buf, int k0) {
#pragma unroll
    for (int i = 0; i < 4; ++i) {
      int c = i * 256 + tid;
      int row = c >> 3;
      int gcol = ((c & 7) ^ (row & 7)) * 8;
      gload_lds16(&A[(rowBase + row) * K + k0 + gcol],
                  &As[buf][(i * 256 + wave * 64) * 8]);
      gload_lds16(&Bt[(colBase + row) * K + k0 + gcol],
                  &Bs[buf][(i * 256 + wave * 64) * 8]);
    }
  };

  stage(0, 0);
  __syncthreads();

  for (int k0 = 0; k0 < K; k0 += 64) {
    const int cur = (k0 >> 6) & 1;
    if (k0 + 64 < K) stage(cur ^ 1, k0 + 64);  // prefetch next tile
#pragma unroll
    for (int kk = 0; kk < 2; ++kk) {
      bf16x8 af[4], bfr[4];
#pragma unroll
      for (int i = 0; i < 4; ++i) {
        int rowA = wr * 64 + i * 16 + l16;
        af[i] = *(const bf16x8*)&As[cur][(rowA * 8 + ((quad + 4 * kk) ^ (rowA & 7))) * 8];
        int rowB = wc * 64 + i * 16 + l16;
        bfr[i] = *(const bf16x8*)&Bs[cur][(rowB * 8 + ((quad + 4 * kk) ^ (rowB & 7))) * 8];
      }
#pragma unroll
      for (int mi = 0; mi < 4; ++mi)
#pragma unroll
        for (int ni = 0; ni < 4; ++ni)
          acc[mi][ni] = __builtin_amdgcn_mfma_f32_16x16x32_bf16(
              af[mi], bfr[ni], acc[mi][ni], 0, 0, 0);
    }
    __syncthreads();  // drains prefetch (overlapped w/ the 64 MFMA above)
  }

#pragma unroll
  for (int mi = 0; mi < 4; ++mi) {
#pragma unroll
    for (int ni = 0; ni < 4; ++ni) {
      int colg = (int)colBase + wc * 64 + ni * 16 + l16;
      float bv = bias[colg];
#pragma unroll
      for (int r = 0; r < 4; ++r) {
        long rowg = rowBase + wr * 64 + mi * 16 + quad * 4 + r;
        float v = acc[mi][ni][r] + bv;
        long idx = rowg * N + colg;
        if (MODE == 0) {
          ((bf16_t*)out)[idx] = (bf16_t)v;
        } else if (MODE == 1) {
          ((float*)out)[idx] = v + resid[idx];
        } else {
          ((bf16_t*)out)[idx] = (bf16_t)fmaxf(v, 0.f);
        }
      }
    }
  }
}

// ---------------------------------------------------------------------------
// V transpose: qkv bf16 [B*T][3072] v-part -> vt bf16 [b*h][d=64][t=2048]
// ---------------------------------------------------------------------------
__global__ __launch_bounds__(256) void vtrans_kernel(
    const bf16_t* __restrict__ qkv, bf16_t* __restrict__ vt) {
  __shared__ bf16_t tile[32][33];
  int tx = threadIdx.x, ty = threadIdx.y;  // (32,8)
  int t0 = blockIdx.x * 32;
  int d0 = (blockIdx.y & 1) * 32;
  int bh = blockIdx.y >> 1;
  int b = bh >> 4, hh = bh & 15;
#pragma unroll
  for (int i = 0; i < 32; i += 8)
    tile[ty + i][tx] =
        qkv[(long)(b * T_ + t0 + ty + i) * LDQ_ + 2 * E_ + hh * HS_ + d0 + tx];
  __syncthreads();
#pragma unroll
  for (int i = 0; i < 32; i += 8)
    vt[((long)bh * HS_ + d0 + ty + i) * T_ + t0 + tx] = tile[tx][ty + i];
}

// ---------------------------------------------------------------------------
// Causal flash attention, KV-split, no-max softmax. S^T form: compute
// S^T = K * Q^T, kv index in register dim: exp'd scores pack into b64 LDS
// writes, l is a per-lane scalar (2 shuffles at end only). Q pre-scaled by
// 0.125 (exact in bf16). O computed transposed; 8B stores.
// Block = 4 waves = 128 Q rows (q-tile ti), KV chunk of <=12 iters of 64.
// splits(ti) = ti/6+1 -> 30 blocks per bh. Multi-split tiles write normalized
// partials merged by flash_merge_kernel with w = l.
// ---------------------------------------------------------------------------
__global__ __launch_bounds__(256) void flash_attn_kernel(
    const bf16_t* __restrict__ qkv, const bf16_t* __restrict__ vt,
    bf16_t* __restrict__ attn, bf16_t* __restrict__ Opart,
    float* __restrict__ mlpart) {
  int gx = blockIdx.x;
  int ti = 0, sp = 0;
  for (int t = 0; t < 16; ++t) {
    int ns = t / 6 + 1;
    if (gx < ns) { ti = t; sp = gx; break; }
    gx -= ns;
  }
  const int nsplit = ti / 6 + 1;
  const int totIt = 2 * (ti + 1);
  const int jbeg = 12 * sp;
  const int jend = min(jbeg + 12, totIt);

  const int tid = threadIdx.x;
  const int lane = tid & 63, wave = tid >> 6;
  const int quad = lane >> 4, l16 = lane & 15;
  const int bh = blockIdx.y, b = bh >> 4, hh = bh & 15;
  const int q0 = ti * 128;
  const int qw = q0 + wave * 32;

  __shared__ __align__(16) bf16_t Ks[64][72];     // [kv][d]
  __shared__ __align__(16) bf16_t Vs[64][72];     // [d][kv]
  __shared__ __align__(16) bf16_t Ps[4][16][72];  // per-wave P^T [q=16][kv=64]

  const bf16_t* qb = qkv;
  const bf16_t* kb = qkv + E_;

  // Q fragments, pre-scaled by HS^-0.5 = 0.125 (power of 2: exact in bf16)
  bf16x8 aq[2][2];
#pragma unroll
  for (int s = 0; s < 2; ++s) {
    long base = (long)(b * T_ + qw + s * 16 + l16) * LDQ_ + hh * HS_ + quad * 8;
    aq[s][0] = *(const bf16x8*)&qb[base];
    aq[s][1] = *(const bf16x8*)&qb[base + 32];
#pragma unroll
    for (int e = 0; e < 8; ++e) {
      aq[s][0][e] = (bf16_t)((float)aq[s][0][e] * 0.125f);
      aq[s][1][e] = (bf16_t)((float)aq[s][1][e] * 0.125f);
    }
  }

  f32x4 o[2][4] = {};     // O^T accumulator: [s][nt]; row d=quad*4+r, col q=l16
  float lsum[2] = {};     // per-lane row sums (q = qs + l16)

  const int srow = tid >> 3;            // 0..31
  const int scol = (tid & 7) * 8;       // bf16 col offset (16B)

  for (int j = jbeg; j < jend; ++j) {
    int kv0 = j * 64;
    // ---- stage K tile [64][64] and V^T tile [64][64] ----
#pragma unroll
    for (int p = 0; p < 2; ++p) {
      int row = p * 32 + srow;
      *(uint4*)&Ks[row][scol] =
          *(const uint4*)&kb[(long)(b * T_ + kv0 + row) * LDQ_ + hh * HS_ + scol];
      *(uint4*)&Vs[row][scol] =
          *(const uint4*)&vt[((long)bh * HS_ + row) * T_ + kv0 + scol];
    }
    __syncthreads();

#pragma unroll
    for (int s = 0; s < 2; ++s) {
      int qs = qw + s * 16;
      if (kv0 <= qs + 15) {
        // ---- S^T = K * Q^T : rows kv (quad*4+r per sub), col q (l16) ----
        f32x4 sc[4];
#pragma unroll
        for (int sub = 0; sub < 4; ++sub) {
          f32x4 t = {};
          t = __builtin_amdgcn_mfma_f32_16x16x32_bf16(
              *(const bf16x8*)&Ks[sub * 16 + l16][quad * 8], aq[s][0], t, 0, 0, 0);
          t = __builtin_amdgcn_mfma_f32_16x16x32_bf16(
              *(const bf16x8*)&Ks[sub * 16 + l16][32 + quad * 8], aq[s][1], t, 0, 0, 0);
          sc[sub] = t;
        }
        // ---- causal mask (diagonal tiles only): kv > q -> -inf ----
        if (kv0 + 63 > qs) {
          int qcol = qs + l16;
#pragma unroll
          for (int sub = 0; sub < 4; ++sub)
#pragma unroll
            for (int r = 0; r < 4; ++r) {
              int kvrow = kv0 + sub * 16 + quad * 4 + r;
              if (kvrow > qcol) sc[sub][r] = -INFINITY;
            }
        }
        // ---- p = exp(s); l accumulates per-lane (all values same q) ----
        float part = 0.f;
#pragma unroll
        for (int sub = 0; sub < 4; ++sub) {
#pragma unroll
          for (int r = 0; r < 4; ++r) sc[sub][r] = __expf(sc[sub][r]);
          part += (sc[sub][0] + sc[sub][1]) + (sc[sub][2] + sc[sub][3]);
        }
        lsum[s] += part;
        // ---- P^T -> LDS: Ps[q][kv], 4 consecutive kv per lane -> b64 ----
#pragma unroll
        for (int sub = 0; sub < 4; ++sub) {
          bf16x4 pk;
#pragma unroll
          for (int r = 0; r < 4; ++r) pk[r] = (bf16_t)sc[sub][r];
          *(bf16x4*)&Ps[wave][l16][sub * 16 + quad * 4] = pk;
        }
        // ---- O^T += V^T * P^T (A=V-frag, B=P-frag; intra-wave, no barrier)
        bf16x8 ap0 = *(const bf16x8*)&Ps[wave][l16][quad * 8];
        bf16x8 ap1 = *(const bf16x8*)&Ps[wave][l16][32 + quad * 8];
#pragma unroll
        for (int nt = 0; nt < 4; ++nt) {
          o[s][nt] = __builtin_amdgcn_mfma_f32_16x16x32_bf16(
              *(const bf16x8*)&Vs[nt * 16 + l16][quad * 8], ap0, o[s][nt], 0, 0, 0);
          o[s][nt] = __builtin_amdgcn_mfma_f32_16x16x32_bf16(
              *(const bf16x8*)&Vs[nt * 16 + l16][32 + quad * 8], ap1, o[s][nt], 0, 0, 0);
        }
      }
    }
    __syncthreads();
  }

  // ---- l reduction across the 4 quads sharing each q ----
  float lval[2];
#pragma unroll
  for (int s = 0; s < 2; ++s) {
    float v = lsum[s];
    v += __shfl_xor(v, 16);
    v += __shfl_xor(v, 32);
    lval[s] = v;
  }

  if (nsplit == 1) {
#pragma unroll
    for (int s = 0; s < 2; ++s) {
      float inv = 1.f / lval[s];
      long rowg = (long)b * T_ + qw + s * 16 + l16;
#pragma unroll
      for (int nt = 0; nt < 4; ++nt) {
        bf16x4 pk;
#pragma unroll
        for (int r = 0; r < 4; ++r) pk[r] = (bf16_t)(o[s][nt][r] * inv);
        *(bf16x4*)&attn[rowg * E_ + hh * HS_ + nt * 16 + quad * 4] = pk;
      }
    }
  } else {
    int idx = (ti < 12) ? (ti - 6) * 2 + sp : 12 + (ti - 12) * 3 + sp;
    long slot = (long)bh * 24 + idx;
    bf16_t* op = Opart + slot * (128 * 64);
    float* ml = mlpart + slot * 256;
#pragma unroll
    for (int s = 0; s < 2; ++s) {
      float inv = 1.f / lval[s];
      int rloc = wave * 32 + s * 16 + l16;
#pragma unroll
      for (int nt = 0; nt < 4; ++nt) {
        bf16x4 pk;
#pragma unroll
        for (int r = 0; r < 4; ++r) pk[r] = (bf16_t)(o[s][nt][r] * inv);
        *(bf16x4*)&op[rloc * 64 + nt * 16 + quad * 4] = pk;
      }
      if (quad == 0) ml[rloc] = lval[s];
    }
  }
}

// ---------------------------------------------------------------------------
// Merge partials for multi-split q-tiles (ti = 6..15): O = sum(l_s*Ohat_s)/sum(l_s)
// grid: (10, 64bh), 256 threads: thread = row(128) * 2 + d-half(32).
// ---------------------------------------------------------------------------
__global__ __launch_bounds__(256) void flash_merge_kernel(
    const bf16_t* __restrict__ Opart, const float* __restrict__ mlpart,
    bf16_t* __restrict__ attn) {
  int ti = 6 + blockIdx.x;
  int bh = blockIdx.y, b = bh >> 4, hh = bh & 15;
  int ns = ti / 6 + 1;
  int base_idx = (ti < 12) ? (ti - 6) * 2 : 12 + (ti - 12) * 3;
  int r = threadIdx.x >> 1;
  int dh = (threadIdx.x & 1) * 32;

  float w[3], den = 0.f;
  for (int s = 0; s < ns; ++s) {
    long slot = (long)bh * 24 + base_idx + s;
    w[s] = mlpart[slot * 256 + r];
    den += w[s];
  }
  float inv = 1.f / den;
  float acc[32];
#pragma unroll
  for (int d = 0; d < 32; ++d) acc[d] = 0.f;
  for (int s = 0; s < ns; ++s) {
    long slot = (long)bh * 24 + base_idx + s;
    const bf16_t* op = Opart + slot * (128 * 64) + r * 64 + dh;
#pragma unroll
    for (int d = 0; d < 32; ++d) acc[d] += w[s] * (float)op[d];
  }
  long rowg = (long)b * T_ + ti * 128 + r;
  bf16_t* dst = attn + rowg * E_ + hh * HS_ + dh;
#pragma unroll
  for (int d = 0; d < 32; ++d) dst[d] = (bf16_t)(acc[d] * inv);
}

// ---------------------------------------------------------------------------
extern "C" void kernel_launch(void* const* d_in, const int* in_sizes, int n_in,
                              void* d_out, int out_size, void* d_ws,
                              size_t ws_size, hipStream_t stream) {
  const float* x = (const float*)d_in[0];
  const float* ln1_g = (const float*)d_in[1];
  const float* ln1_b = (const float*)d_in[2];
  const float* Wq = (const float*)d_in[3];
  const float* bq = (const float*)d_in[4];
  const float* Wk = (const float*)d_in[5];
  const float* bk = (const float*)d_in[6];
  const float* Wv = (const float*)d_in[7];
  const float* bv = (const float*)d_in[8];
  const float* Wp = (const float*)d_in[9];
  const float* bp = (const float*)d_in[10];
  const float* ln2_g = (const float*)d_in[11];
  const float* ln2_b = (const float*)d_in[12];
  const float* W1 = (const float*)d_in[13];
  const float* b1 = (const float*)d_in[14];
  const float* W2 = (const float*)d_in[15];
  const float* b2 = (const float*)d_in[16];
  float* out = (float*)d_out;

  const size_t MB = 1ull << 20;
  char* ws = (char*)d_ws;
  bf16_t* wqkvt = (bf16_t*)(ws + 0 * MB);   // [3072][1024] bf16 = 6 MB
  bf16_t* wpt   = (bf16_t*)(ws + 6 * MB);   // 2 MB
  bf16_t* w1t   = (bf16_t*)(ws + 8 * MB);   // 8 MB
  bf16_t* w2t   = (bf16_t*)(ws + 16 * MB);  // 8 MB
  float*  bqkv  = (float*)(ws + 24 * MB);   // 12 KB
  bf16_t* h     = (bf16_t*)(ws + 25 * MB);  // [8192][1024] 16 MB; reused: attn, h2
  bf16_t* qkvb  = (bf16_t*)(ws + 41 * MB);  // [8192][3072] 48 MB; reused: ff1
  bf16_t* vt    = (bf16_t*)(ws + 89 * MB);  // [64][64][2048] 16 MB
  float*  xmid  = (float*)(ws + 105 * MB);  // 32 MB -> ends 137 MB
  // flash scratch overlaps xmid temporally (dead before proj writes xmid):
  bf16_t* Opart = (bf16_t*)(ws + 105 * MB); // 1536 slots * 8192 bf16 = 25.2 MB
  float* mlpart = (float*)(ws + 131 * MB);  // 1536 * 256 fp32 = 1.5 MB
  bf16_t* attn  = h;                        // h dead after QKV gemm
  bf16_t* h2    = h;                        // attn dead after proj gemm
  bf16_t* ff1   = qkvb;                     // qkv+vt dead after flash

  dim3 tb(32, 8);
  // weight transposes into fused QKV layout [3072][1024]
  wtrans_kernel<<<dim3(E_ / 32, E_ / 32), tb, 0, stream>>>(Wq, wqkvt, E_, E_);
  wtrans_kernel<<<dim3(E_ / 32, E_ / 32), tb, 0, stream>>>(Wk, wqkvt + (long)E_ * E_, E_, E_);
  wtrans_kernel<<<dim3(E_ / 32, E_ / 32), tb, 0, stream>>>(Wv, wqkvt + 2l * E_ * E_, E_, E_);
  wtrans_kernel<<<dim3(E_ / 32, E_ / 32), tb, 0, stream>>>(Wp, wpt, E_, E_);
  wtrans_kernel<<<dim3(DFF_ / 32, E_ / 32), tb, 0, stream>>>(W1, w1t, E_, DFF_);
  wtrans_kernel<<<dim3(E_ / 32, DFF_ / 32), tb, 0, stream>>>(W2, w2t, DFF_, E_);
  bcat_kernel<<<12, 256, 0, stream>>>(bq, bk, bv, bqkv);

  // LN1
  layernorm_kernel<<<M_, 256, 0, stream>>>(x, ln1_g, ln1_b, h);

  // fused QKV gemm: [8192][3072]
  gemm_bt_kernel<0><<<dim3(3 * E_ / 128, M_ / 128), 256, 0, stream>>>(
      h, wqkvt, bqkv, nullptr, qkvb, 3 * E_, E_);

  // V transpose to [bh][d][t]
  vtrans_kernel<<<dim3(T_ / 32, 2 * B_ * H_), tb, 0, stream>>>(qkvb, vt);

  // flash attention, KV-split (30 uniform blocks per bh) + merge
  flash_attn_kernel<<<dim3(30, B_ * H_), 256, 0, stream>>>(qkvb, vt, attn,
                                                           Opart, mlpart);
  flash_merge_kernel<<<dim3(10, B_ * H_), 256, 0, stream>>>(Opart, mlpart, attn);

  // proj + residual -> xmid (fp32)
  gemm_bt_kernel<1><<<dim3(E_ / 128, M_ / 128), 256, 0, stream>>>(
      attn, wpt, bp, x, xmid, E_, E_);

  // LN2
  layernorm_kernel<<<M_, 256, 0, stream>>>(xmid, ln2_g, ln2_b, h2);

  // FFN
  gemm_bt_kernel<2><<<dim3(DFF_ / 128, M_ / 128), 256, 0, stream>>>(
      h2, w1t, b1, nullptr, ff1, DFF_, E_);
  gemm_bt_kernel<1><<<dim3(E_ / 128, M_ / 128), 256, 0, stream>>>(
      ff1, w2t, b2, xmid, out, E_, DFF_);
}